// Round 2
// baseline (488.698 us; speedup 1.0000x reference)
//
#include <hip/hip_runtime.h>

#define B_ 64
#define T_ 512
#define F_ 1024
#define U_ 64

// ---------------------------------------------------------------------------
// Kernel 1: potentials[n][u] = x[n][:] . kernel[:][u] + bias[u] (+ boundaries)
// 32768 rows x 64 cols. 2 rows x 4 cols per thread, K unrolled by 8.
// grid = 1024 blocks -> 4 blocks/CU = 4 waves/SIMD (was 1 -> latency-bound).
// Accumulation order identical to the validated kernel: ascending f,
// sequential fmaf per (row, col).
// ---------------------------------------------------------------------------
__global__ __launch_bounds__(256, 4) void crf_gemm_kernel(
    const float* __restrict__ x, const float* __restrict__ w,
    const float* __restrict__ bias, const float* __restrict__ lb,
    const float* __restrict__ rb, float* __restrict__ pot)
{
    const int tid = threadIdx.x;
    const int rt = tid >> 4;        // 16 row-groups x 2 rows
    const int ut = tid & 15;        // 16 col-groups x 4 cols
    const int n0 = blockIdx.x * 32;
    const int r0 = rt * 2;
    const int u0 = ut * 4;

    float acc0[4] = {0.f, 0.f, 0.f, 0.f};
    float acc1[4] = {0.f, 0.f, 0.f, 0.f};

    const float* xp = x + (size_t)(n0 + r0) * F_;
    const float* wp = w + u0;

    for (int it = 0; it < F_ / 8; ++it) {
        const float4 xa0 = *reinterpret_cast<const float4*>(xp);
        const float4 xb0 = *reinterpret_cast<const float4*>(xp + 4);
        const float4 xa1 = *reinterpret_cast<const float4*>(xp + F_);
        const float4 xb1 = *reinterpret_cast<const float4*>(xp + F_ + 4);
        float4 kv[8];
#pragma unroll
        for (int ff = 0; ff < 8; ++ff)
            kv[ff] = *reinterpret_cast<const float4*>(wp + ff * U_);

        const float xr0[8] = {xa0.x, xa0.y, xa0.z, xa0.w, xb0.x, xb0.y, xb0.z, xb0.w};
        const float xr1[8] = {xa1.x, xa1.y, xa1.z, xa1.w, xb1.x, xb1.y, xb1.z, xb1.w};
#pragma unroll
        for (int ff = 0; ff < 8; ++ff) {
            acc0[0] = fmaf(xr0[ff], kv[ff].x, acc0[0]);
            acc0[1] = fmaf(xr0[ff], kv[ff].y, acc0[1]);
            acc0[2] = fmaf(xr0[ff], kv[ff].z, acc0[2]);
            acc0[3] = fmaf(xr0[ff], kv[ff].w, acc0[3]);
            acc1[0] = fmaf(xr1[ff], kv[ff].x, acc1[0]);
            acc1[1] = fmaf(xr1[ff], kv[ff].y, acc1[1]);
            acc1[2] = fmaf(xr1[ff], kv[ff].z, acc1[2]);
            acc1[3] = fmaf(xr1[ff], kv[ff].w, acc1[3]);
        }
        xp += 8;
        wp += 8 * U_;
    }

    const int t0 = n0 & (T_ - 1);   // 32 | 512: block never crosses a batch
    const float4 bs4 = *reinterpret_cast<const float4*>(bias + u0);
    const float4 lb4 = *reinterpret_cast<const float4*>(lb + u0);
    const float4 rb4 = *reinterpret_cast<const float4*>(rb + u0);

#pragma unroll
    for (int i = 0; i < 2; ++i) {
        const float* a = (i == 0) ? acc0 : acc1;
        const int n = n0 + r0 + i;
        const int t = t0 + r0 + i;
        float4 o;
        o.x = a[0] + bs4.x;
        o.y = a[1] + bs4.y;
        o.z = a[2] + bs4.z;
        o.w = a[3] + bs4.w;
        if (t == 0)      { o.x += lb4.x; o.y += lb4.y; o.z += lb4.z; o.w += lb4.w; }
        if (t == T_ - 1) { o.x += rb4.x; o.y += rb4.y; o.z += rb4.z; o.w += rb4.w; }
        *reinterpret_cast<float4*>(pot + (size_t)n * U_ + u0) = o;
    }
}

// ---------------------------------------------------------------------------
// Kernel 2: Viterbi forward + backtrace, one block (4 waves) per batch.
// Thread (g, u): v in [g*16, g*16+16) for output tag u. Proven 2-barrier
// skeleton; new: tournament-tree max/argmax (ILP, left-wins-ties == first
// occurrence), redundant cross-group combine on all waves, and per-wave
// register chunk-maps (ds_bpermute composition) so the backtrace is 4
// parallel 128-deep chases instead of one 511-deep chase.
// Exact reference arithmetic: s = (alpha[v] + chain[v][u]) + pot[t][u],
// strict > , ascending v  == jnp.argmax first-occurrence.
// ---------------------------------------------------------------------------
__global__ __launch_bounds__(256) void crf_viterbi_kernel(
    const float* __restrict__ pot, const float* __restrict__ chain,
    int* __restrict__ path)
{
    const int b = blockIdx.x;
    const int tid = threadIdx.x;
    const int u = tid & 63;
    const int g = tid >> 6;   // wave id 0..3

    __shared__ __align__(16) float alpha_s[64];
    __shared__ float pval[4][64];
    __shared__ int   pidx[4][64];
    __shared__ unsigned char bp[T_ - 1][64];   // 32704 B
    __shared__ int cmap[4][64];
    __shared__ int es[4];
    __shared__ int last_s;

    float chain_r[16];
#pragma unroll
    for (int k = 0; k < 16; ++k)
        chain_r[k] = chain[(size_t)(g * 16 + k) * U_ + u];

    const float* potb = pot + (size_t)b * T_ * U_;

    if (g == 0) alpha_s[u] = potb[u];          // t = 0 (bias + left included)
    __syncthreads();

    float pc = potb[U_ + u];                   // pot[1][u]
    int C = u;                                 // identity chunk map (per wave)
    const int r0c = g * 128;
    const int r1c = (g == 3) ? (T_ - 1) : (g + 1) * 128;

    for (int t = 1; t < T_; ++t) {
        const int tn = (t + 1 < T_) ? (t + 1) : (T_ - 1);
        const float pn = potb[(size_t)tn * U_ + u];

        // s[k] = (alpha[g*16+k] + chain[g*16+k][u]) + pot[t][u]
        const float4* a4 = reinterpret_cast<const float4*>(alpha_s);
        float s[16];
#pragma unroll
        for (int q = 0; q < 4; ++q) {
            const float4 av = a4[g * 4 + q];
            s[q * 4 + 0] = (av.x + chain_r[q * 4 + 0]) + pc;
            s[q * 4 + 1] = (av.y + chain_r[q * 4 + 1]) + pc;
            s[q * 4 + 2] = (av.z + chain_r[q * 4 + 2]) + pc;
            s[q * 4 + 3] = (av.w + chain_r[q * 4 + 3]) + pc;
        }
        // tournament: strict >, left (smaller k) wins ties -> first occurrence
        float tv[8]; int ti[8];
#pragma unroll
        for (int i = 0; i < 8; ++i) {
            const bool gt = s[2 * i + 1] > s[2 * i];
            tv[i] = gt ? s[2 * i + 1] : s[2 * i];
            ti[i] = gt ? 2 * i + 1 : 2 * i;
        }
        float uv[4]; int ui[4];
#pragma unroll
        for (int i = 0; i < 4; ++i) {
            const bool gt = tv[2 * i + 1] > tv[2 * i];
            uv[i] = gt ? tv[2 * i + 1] : tv[2 * i];
            ui[i] = gt ? ti[2 * i + 1] : ti[2 * i];
        }
        const bool gw0 = uv[1] > uv[0];
        const float wv0 = gw0 ? uv[1] : uv[0];
        const int   wi0 = gw0 ? ui[1] : ui[0];
        const bool gw1 = uv[3] > uv[2];
        const float wv1 = gw1 ? uv[3] : uv[2];
        const int   wi1 = gw1 ? ui[3] : ui[2];
        const bool gf = wv1 > wv0;
        const float bv16 = gf ? wv1 : wv0;
        const int   bi16 = gf ? wi1 : wi0;

        pval[g][u] = bv16;
        pidx[g][u] = g * 16 + bi16;
        __syncthreads();

        // redundant combine (ascending g, strict > -> lowest g wins ties)
        const float p0 = pval[0][u], p1 = pval[1][u];
        const float p2 = pval[2][u], p3 = pval[3][u];
        const int   j0 = pidx[0][u], j1 = pidx[1][u];
        const int   j2 = pidx[2][u], j3 = pidx[3][u];
        const bool ga = p1 > p0; const float va = ga ? p1 : p0; const int ia = ga ? j1 : j0;
        const bool gb = p3 > p2; const float vb = gb ? p3 : p2; const int ib = gb ? j3 : j2;
        const bool gc = vb > va; const float bv = gc ? vb : va; const int bi = gc ? ib : ia;

        if (g == 0) {
            alpha_s[u] = bv;
            bp[t - 1][u] = (unsigned char)bi;
        }
        // compose this row into my chunk's map: C_new[u] = C_old[bi[u]]
        const int r = t - 1;
        if (r >= r0c && r < r1c)
            C = __builtin_amdgcn_ds_bpermute(bi << 2, C);
        __syncthreads();
        pc = pn;
    }

    cmap[g][u] = C;
    if (tid == 0) {
        // final argmax over alpha (first occurrence)
        float bvv = alpha_s[0];
        int bii = 0;
        for (int v = 1; v < 64; ++v) {
            const float a = alpha_s[v];
            if (a > bvv) { bvv = a; bii = v; }
        }
        last_s = bii;
        path[(size_t)b * T_ + (T_ - 1)] = bii;
    }
    __syncthreads();
    if (tid == 0) {
        // boundary tags via chunk maps: cmap[g](tag at r1c) = tag at r0c
        const int e3 = last_s;           // tag_{511}
        const int e2 = cmap[3][e3];      // tag_{384}
        const int e1 = cmap[2][e2];      // tag_{256}
        const int e0 = cmap[1][e1];      // tag_{128}
        es[0] = e0; es[1] = e1; es[2] = e2; es[3] = e3;
    }
    __syncthreads();
    if (u == 0) {
        // 4 parallel chases, one per wave, over disjoint row ranges
        int tag = es[g];
        int* pb = path + (size_t)b * T_;
        for (int r = r1c - 1; r >= r0c; --r) {
            tag = bp[r][tag];
            pb[r] = tag;
        }
    }
}

extern "C" void kernel_launch(void* const* d_in, const int* in_sizes, int n_in,
                              void* d_out, int out_size, void* d_ws, size_t ws_size,
                              hipStream_t stream) {
    const float* x  = (const float*)d_in[0];
    const float* w  = (const float*)d_in[1];
    const float* bs = (const float*)d_in[2];
    const float* ck = (const float*)d_in[3];
    const float* lb = (const float*)d_in[4];
    const float* rb = (const float*)d_in[5];

    float* pot = (float*)d_ws;          // [B*T][U] f32 = 8.39 MB
    int* path  = (int*)d_out;           // [B][T] int32

    crf_gemm_kernel<<<dim3(B_ * T_ / 32), dim3(256), 0, stream>>>(x, w, bs, lb, rb, pot);
    crf_viterbi_kernel<<<dim3(B_), dim3(256), 0, stream>>>(pot, ck, path);
}